// Round 19
// baseline (410.845 us; speedup 1.0000x reference)
//
#include <hip/hip_runtime.h>
#include <stdint.h>

#define DEV __device__ __forceinline__

typedef __attribute__((ext_vector_type(8))) short bf16x8;
typedef __attribute__((ext_vector_type(4))) float f32x4;
typedef __attribute__((ext_vector_type(16))) float f32x16;
typedef __attribute__((ext_vector_type(4))) unsigned u32x4;

#define NTOT 2304

DEV unsigned short f2bf(float f) {
  union { float f; unsigned u; } c; c.f = f;
  return (unsigned short)((c.u + 0x7FFFu + ((c.u >> 16) & 1u)) >> 16);
}
DEV unsigned pack2(float lo, float hi) {
  return ((unsigned)f2bf(hi) << 16) | (unsigned)f2bf(lo);
}
DEV unsigned cvtpk(float lo, float hi) {
  unsigned r;
  asm("v_cvt_pk_bf16_f32 %0, %1, %2" : "=v"(r) : "v"(lo), "v"(hi));
  return r;
}
DEV float bf2f(short x) {
  union { unsigned u; float f; } c; c.u = ((unsigned)(unsigned short)x) << 16; return c.f;
}
DEV void gload_lds16(const void* g, void* l) {
  __builtin_amdgcn_global_load_lds(
      (const __attribute__((address_space(1))) unsigned int*)g,
      (__attribute__((address_space(3))) unsigned int*)l, 16, 0, 0);
}
DEV void pl32swap(unsigned& a, unsigned& b) {
  asm volatile("v_permlane32_swap_b32 %0, %1" : "+v"(a), "+v"(b));
}

// ---------------- merged RMS-modulated norm (x rows then y rows) ----------------
__global__ __launch_bounds__(256) void k_modnorm(const float* __restrict__ X,
                                                 const float* __restrict__ scale_x,
                                                 short* __restrict__ outx,
                                                 const float* __restrict__ Y,
                                                 const float* __restrict__ scale_y,
                                                 short* __restrict__ outy) {
  int row = blockIdx.x;
  const float* x;
  const float* scale;
  short* o;
  int D;
  if (row < 2048) {
    x = X + (size_t)row * 3072; scale = scale_x; o = outx + (size_t)row * 3072; D = 3072;
  } else {
    row -= 2048;
    x = Y + (size_t)row * 1536; scale = scale_y; o = outy + (size_t)row * 1536; D = 1536;
  }
  float ss = 0.f;
  for (int v = threadIdx.x * 4; v < D; v += 1024) {
    float4 a = *(const float4*)(x + v);
    ss += a.x * a.x + a.y * a.y + a.z * a.z + a.w * a.w;
  }
#pragma unroll
  for (int m = 1; m < 64; m <<= 1) ss += __shfl_xor(ss, m);
  __shared__ float red[4];
  if ((threadIdx.x & 63) == 0) red[threadIdx.x >> 6] = ss;
  __syncthreads();
  float tot = red[0] + red[1] + red[2] + red[3];
  float r = rsqrtf(tot / (float)D + 1e-6f);
  for (int v = threadIdx.x * 4; v < D; v += 1024) {
    float4 a = *(const float4*)(x + v);
    float4 s = *(const float4*)(scale + v);
    uint2 pk;
    pk.x = pack2(a.x * r * (1.f + s.x), a.y * r * (1.f + s.y));
    pk.y = pack2(a.z * r * (1.f + s.z), a.w * r * (1.f + s.w));
    *(uint2*)(o + v) = pk;
  }
}

// ---------------- fused 4-segment f32 -> bf16 convert ----------------
__global__ __launch_bounds__(256) void k_cvt4(const float* __restrict__ s0, short* __restrict__ d0, int n0,
                                              const float* __restrict__ s1, short* __restrict__ d1, int n1,
                                              const float* __restrict__ s2, short* __restrict__ d2, int n2,
                                              const float* __restrict__ s3, short* __restrict__ d3, int n3) {
  int total = n0 + n1 + n2 + n3;
  int stride = gridDim.x * blockDim.x;
  for (int i = blockIdx.x * blockDim.x + threadIdx.x; i < total; i += stride) {
    const float* s; short* d; int j = i;
    if (j < n0) { s = s0; d = d0; }
    else {
      j -= n0;
      if (j < n1) { s = s1; d = d1; }
      else {
        j -= n1;
        if (j < n2) { s = s2; d = d2; }
        else { j -= n2; s = s3; d = d3; }
      }
    }
    float4 a = *(const float4*)(s + (size_t)j * 4);
    uint2 pk;
    pk.x = pack2(a.x, a.y);
    pk.y = pack2(a.z, a.w);
    *(uint2*)(d + (size_t)j * 4) = pk;
  }
}

// ---------------- merged proj GEMM: proj_x (blocks 0..383) + proj_y (384..407) ----------
__global__ __launch_bounds__(256) void k_gemm2(const short* __restrict__ A1,
                                               const short* __restrict__ B1,
                                               const float* __restrict__ b1,
                                               float* __restrict__ C1,
                                               const short* __restrict__ A2,
                                               const short* __restrict__ B2,
                                               const float* __restrict__ b2,
                                               float* __restrict__ C2) {
  const int K = 3072;
  int bid = blockIdx.x;
  const short* A; const short* B; const float* bias; float* C;
  int bx, by, N;
  if (bid < 384) {
    bx = bid % 24; by = bid / 24;
    A = A1; B = B1; bias = b1; C = C1; N = 3072;
  } else {
    int j = bid - 384;
    bx = j % 12; by = j / 12;
    A = A2; B = B2; bias = b2; C = C2; N = 1536;
  }
  __shared__ __align__(16) char As[16384];
  __shared__ __align__(16) char Bs[16384];
  const int tid = threadIdx.x;
  const int brow = by * 128, bcol = bx * 128;
  const int w = tid >> 6, l = tid & 63;
  const int wr = (w >> 1) * 64, wc = (w & 1) * 64;
  const int lr = l & 15, lg = l >> 4;
  f32x4 acc[4][4];
#pragma unroll
  for (int m = 0; m < 4; ++m)
#pragma unroll
    for (int n = 0; n < 4; ++n) acc[m][n] = (f32x4){0.f, 0.f, 0.f, 0.f};
  for (int k0 = 0; k0 < K; k0 += 64) {
#pragma unroll
    for (int it = 0; it < 4; ++it) {
      int o = it * 4096 + tid * 16;
      int row = o >> 7;
      int gs = ((o >> 4) & 7) ^ (row & 7);
      gload_lds16(A + (size_t)(brow + row) * K + k0 + gs * 8, As + o);
      gload_lds16(B + (size_t)(bcol + row) * K + k0 + gs * 8, Bs + o);
    }
    __syncthreads();
#pragma unroll
    for (int ks = 0; ks < 2; ++ks) {
      bf16x8 af[4], bfr[4];
#pragma unroll
      for (int m = 0; m < 4; ++m) {
        int ra = wr + m * 16 + lr;
        af[m] = *(const bf16x8*)(As + ra * 128 + (((ks * 4 + lg) ^ (ra & 7)) << 4));
        int rb = wc + m * 16 + lr;
        bfr[m] = *(const bf16x8*)(Bs + rb * 128 + (((ks * 4 + lg) ^ (rb & 7)) << 4));
      }
#pragma unroll
      for (int m = 0; m < 4; ++m)
#pragma unroll
        for (int n = 0; n < 4; ++n)
          acc[m][n] = __builtin_amdgcn_mfma_f32_16x16x32_bf16(bfr[n], af[m], acc[m][n], 0, 0, 0);
    }
    __syncthreads();
  }
#pragma unroll
  for (int m = 0; m < 4; ++m) {
    int row = brow + wr + m * 16 + lr;
#pragma unroll
    for (int n = 0; n < 4; ++n) {
      int col = bcol + wc + n * 16 + lg * 4;
      float4 bv = *(const float4*)(bias + col);
      float4 o;
      o.x = acc[m][n][0] + bv.x;
      o.y = acc[m][n][1] + bv.y;
      o.z = acc[m][n][2] + bv.z;
      o.w = acc[m][n][3] + bv.w;
      *(float4*)(C + (size_t)row * N + col) = o;
    }
  }
}

// ---------------- merged qkv GEMM: x-tail (blocks 0..127) + y (128..271) ----------------
__global__ __launch_bounds__(256) void k_gemm_qkv2(const short* __restrict__ Ax,
                                                   const short* __restrict__ Bx,
                                                   const float* __restrict__ biasx,
                                                   const short* __restrict__ Ay,
                                                   const short* __restrict__ By,
                                                   const float* __restrict__ biasy,
                                                   short* __restrict__ Qb, short* __restrict__ Kb,
                                                   short* __restrict__ Vb) {
  int bid = blockIdx.x;
  const short* A; const short* B; const float* bias;
  int K, col0, base_n, bx, by;
  if (bid < 128) {
    bx = bid & 7; by = bid >> 3;
    A = Ax; B = Bx; bias = biasx; K = 3072; col0 = 8192; base_n = 0;
  } else {
    int j = bid - 128;
    bx = j % 72; by = j / 72;
    A = Ay; B = By; bias = biasy; K = 1536; col0 = 0; base_n = 2048;
  }
  __shared__ __align__(16) char As[16384];
  __shared__ __align__(16) char Bs[16384];
  const int tid = threadIdx.x;
  const int brow = by * 128, bcol = bx * 128;
  const int w = tid >> 6, l = tid & 63;
  const int wr = (w >> 1) * 64, wc = (w & 1) * 64;
  const int lr = l & 15, lg = l >> 4;
  f32x4 acc[4][4];
#pragma unroll
  for (int m = 0; m < 4; ++m)
#pragma unroll
    for (int n = 0; n < 4; ++n) acc[m][n] = (f32x4){0.f, 0.f, 0.f, 0.f};
  for (int k0 = 0; k0 < K; k0 += 64) {
#pragma unroll
    for (int it = 0; it < 4; ++it) {
      int o = it * 4096 + tid * 16;
      int row = o >> 7;
      int gs = ((o >> 4) & 7) ^ (row & 7);
      gload_lds16(A + (size_t)(brow + row) * K + k0 + gs * 8, As + o);
      gload_lds16(B + (size_t)(bcol + row) * K + k0 + gs * 8, Bs + o);
    }
    __syncthreads();
#pragma unroll
    for (int ks = 0; ks < 2; ++ks) {
      bf16x8 af[4], bfr[4];
#pragma unroll
      for (int m = 0; m < 4; ++m) {
        int ra = wr + m * 16 + lr;
        af[m] = *(const bf16x8*)(As + ra * 128 + (((ks * 4 + lg) ^ (ra & 7)) << 4));
        int rb = wc + m * 16 + lr;
        bfr[m] = *(const bf16x8*)(Bs + rb * 128 + (((ks * 4 + lg) ^ (rb & 7)) << 4));
      }
#pragma unroll
      for (int m = 0; m < 4; ++m)
#pragma unroll
        for (int n = 0; n < 4; ++n)
          acc[m][n] = __builtin_amdgcn_mfma_f32_16x16x32_bf16(bfr[n], af[m], acc[m][n], 0, 0, 0);
    }
    __syncthreads();
  }
#pragma unroll
  for (int m = 0; m < 4; ++m) {
    int row = brow + wr + m * 16 + lr;
#pragma unroll
    for (int n = 0; n < 4; ++n) {
      int colg = col0 + bcol + wc + n * 16 + lg * 4;
      float4 bv = *(const float4*)(bias + colg);
      int ty = colg / 3072;
      int rem = colg - ty * 3072;
      int h = rem >> 7, d = rem & 127;
      short* dst = (ty == 0) ? Qb : ((ty == 1) ? Kb : Vb);
      uint2 pk;
      pk.x = pack2(acc[m][n][0] + bv.x, acc[m][n][1] + bv.y);
      pk.y = pack2(acc[m][n][2] + bv.z, acc[m][n][3] + bv.w);
      *(uint2*)(dst + ((size_t)(h * NTOT + base_n + row)) * 128 + d) = pk;
    }
  }
}

// ---------------- 256x256 pipelined GEMM, bf16 qkv epilogue ----------------
__global__ __launch_bounds__(512, 2) void k_g256(const short* __restrict__ A,
                                                 const short* __restrict__ B,
                                                 const float* __restrict__ bias,
                                                 short* __restrict__ Qb, short* __restrict__ Kb,
                                                 short* __restrict__ Vb, int K) {
  __shared__ __align__(16) char lds[131072];  // 2 x (A 32K | B 32K)
  const int tid = threadIdx.x;
  const int w = tid >> 6, l = tid & 63;
  const int lr = l & 15, lg = l >> 4;
  const int wm = w >> 2, wn = w & 3;
  const int brow = blockIdx.y * 256, bcol = blockIdx.x * 256;
  const int nt = K >> 6;

  auto issue = [&](int g) {
    if (g >= 4 * nt) return;
    int tt = g >> 2, hh = g & 3;
    char* base = lds + (tt & 1) * 65536;
    if (hh < 2) {
#pragma unroll
      for (int j = 0; j < 2; ++j) {
        int ch = hh * 1024 + j * 512 + tid;
        int row = ch >> 3, c = ch & 7;
        gload_lds16(A + (size_t)(brow + row) * K + tt * 64 + ((c ^ (row & 7)) << 3),
                    base + ch * 16);
      }
    } else {
      int hb = hh - 2;
#pragma unroll
      for (int j = 0; j < 2; ++j) {
        int ch = hb * 1024 + j * 512 + tid;
        int row = ch >> 3, c = ch & 7;
        gload_lds16(B + (size_t)(bcol + row) * K + tt * 64 + ((c ^ (row & 7)) << 3),
                    base + 32768 + ch * 16);
      }
    }
  };

  f32x4 acc[8][4];
#pragma unroll
  for (int m = 0; m < 8; ++m)
#pragma unroll
    for (int n = 0; n < 4; ++n) acc[m][n] = (f32x4){0.f, 0.f, 0.f, 0.f};

#pragma unroll
  for (int g = 0; g < 6; ++g) issue(g);
  asm volatile("s_waitcnt vmcnt(4)" ::: "memory");
  __builtin_amdgcn_s_barrier();

  bf16x8 af[8][2], bf[4][2];
  for (int t = 0; t < nt; ++t) {
    const char* bb = lds + (t & 1) * 65536;
    const int g0 = 4 * t + 6;
    // p0
#pragma unroll
    for (int m = 0; m < 4; ++m) {
      int r = wm * 128 + m * 16 + lr;
#pragma unroll
      for (int ks = 0; ks < 2; ++ks)
        af[m][ks] = *(const bf16x8*)(bb + r * 128 + (((ks * 4 + lg) ^ (r & 7)) << 4));
    }
#pragma unroll
    for (int n = 0; n < 2; ++n) {
      int r = wn * 64 + n * 16 + lr;
#pragma unroll
      for (int ks = 0; ks < 2; ++ks)
        bf[n][ks] = *(const bf16x8*)(bb + 32768 + r * 128 + (((ks * 4 + lg) ^ (r & 7)) << 4));
    }
    issue(g0);
    __builtin_amdgcn_s_barrier();
    __builtin_amdgcn_s_setprio(1);
#pragma unroll
    for (int m = 0; m < 4; ++m)
#pragma unroll
      for (int n = 0; n < 2; ++n)
#pragma unroll
        for (int ks = 0; ks < 2; ++ks)
          acc[m][n] = __builtin_amdgcn_mfma_f32_16x16x32_bf16(bf[n][ks], af[m][ks], acc[m][n], 0, 0, 0);
    __builtin_amdgcn_s_setprio(0);
    __builtin_amdgcn_sched_barrier(0);
    __builtin_amdgcn_s_barrier();
    // p1
#pragma unroll
    for (int m = 4; m < 8; ++m) {
      int r = wm * 128 + m * 16 + lr;
#pragma unroll
      for (int ks = 0; ks < 2; ++ks)
        af[m][ks] = *(const bf16x8*)(bb + r * 128 + (((ks * 4 + lg) ^ (r & 7)) << 4));
    }
#pragma unroll
    for (int n = 2; n < 4; ++n) {
      int r = wn * 64 + n * 16 + lr;
#pragma unroll
      for (int ks = 0; ks < 2; ++ks)
        bf[n][ks] = *(const bf16x8*)(bb + 32768 + r * 128 + (((ks * 4 + lg) ^ (r & 7)) << 4));
    }
    issue(g0 + 1);
    __builtin_amdgcn_s_barrier();
    __builtin_amdgcn_s_setprio(1);
#pragma unroll
    for (int m = 4; m < 8; ++m)
#pragma unroll
      for (int n = 2; n < 4; ++n)
#pragma unroll
        for (int ks = 0; ks < 2; ++ks)
          acc[m][n] = __builtin_amdgcn_mfma_f32_16x16x32_bf16(bf[n][ks], af[m][ks], acc[m][n], 0, 0, 0);
    __builtin_amdgcn_s_setprio(0);
    __builtin_amdgcn_sched_barrier(0);
    __builtin_amdgcn_s_barrier();
    // p2
    issue(g0 + 2);
    __builtin_amdgcn_s_barrier();
    __builtin_amdgcn_s_setprio(1);
#pragma unroll
    for (int m = 0; m < 4; ++m)
#pragma unroll
      for (int n = 2; n < 4; ++n)
#pragma unroll
        for (int ks = 0; ks < 2; ++ks)
          acc[m][n] = __builtin_amdgcn_mfma_f32_16x16x32_bf16(bf[n][ks], af[m][ks], acc[m][n], 0, 0, 0);
    __builtin_amdgcn_s_setprio(0);
    __builtin_amdgcn_sched_barrier(0);
    __builtin_amdgcn_s_barrier();
    // p3
    issue(g0 + 3);
    __builtin_amdgcn_s_barrier();
    __builtin_amdgcn_s_setprio(1);
#pragma unroll
    for (int m = 4; m < 8; ++m)
#pragma unroll
      for (int n = 0; n < 2; ++n)
#pragma unroll
        for (int ks = 0; ks < 2; ++ks)
          acc[m][n] = __builtin_amdgcn_mfma_f32_16x16x32_bf16(bf[n][ks], af[m][ks], acc[m][n], 0, 0, 0);
    __builtin_amdgcn_s_setprio(0);
    __builtin_amdgcn_sched_barrier(0);
    if (t + 2 < nt)
      asm volatile("s_waitcnt vmcnt(4)" ::: "memory");
    else
      asm volatile("s_waitcnt vmcnt(0)" ::: "memory");
    __builtin_amdgcn_s_barrier();
  }

  // epilogue: bias + packed 8B bf16 stores (lane holds 4 consecutive cols)
#pragma unroll
  for (int m = 0; m < 8; ++m) {
    int row = brow + wm * 128 + m * 16 + lr;
#pragma unroll
    for (int n = 0; n < 4; ++n) {
      int colg = bcol + wn * 64 + n * 16 + lg * 4;
      float4 bv = *(const float4*)(bias + colg);
      int ty = colg / 3072;
      int rem = colg - ty * 3072;
      int h = rem >> 7, d = rem & 127;
      short* dst = (ty == 0) ? Qb : ((ty == 1) ? Kb : Vb);
      uint2 pk;
      pk.x = pack2(acc[m][n][0] + bv.x, acc[m][n][1] + bv.y);
      pk.y = pack2(acc[m][n][2] + bv.z, acc[m][n][3] + bv.w);
      *(uint2*)(dst + ((size_t)(h * NTOT + row)) * 128 + d) = pk;
    }
  }
}

// ---------------- merged: qkv post (blocks 0..13823) + V transpose (13824..15551) ----------
__global__ __launch_bounds__(256) void k_post2t(short* __restrict__ Qb, short* __restrict__ Kb,
                                                const float* __restrict__ wqx,
                                                const float* __restrict__ wkx,
                                                const float* __restrict__ wqy,
                                                const float* __restrict__ wky,
                                                const float* __restrict__ cosb,
                                                const float* __restrict__ sinb,
                                                const short* __restrict__ V,
                                                short* __restrict__ VT) {
  __shared__ __align__(16) short tile[64][72];
  int bid = blockIdx.x;
  if (bid < 13824) {
    // ---- post2: RMS(head) [+RoPE for x-part] on Q,K in place ----
    int idx = bid * 4 + (threadIdx.x >> 6);
    int l = threadIdx.x & 63;
    const float* wq;
    const float* wk;
    int n, h, base_n;
    bool rope;
    if (idx < 49152) {
      n = idx / 24; h = idx - n * 24; base_n = 0; wq = wqx; wk = wkx; rope = true;
    } else {
      int j = idx - 49152;
      n = j / 24; h = j - n * 24; base_n = 2048; wq = wqy; wk = wky; rope = false;
    }
    size_t off = ((size_t)h * NTOT + base_n + n) * 128 + 2 * l;
    unsigned qu = *(unsigned*)(Qb + off);
    unsigned ku = *(unsigned*)(Kb + off);
    float qx = bf2f((short)(qu & 0xFFFF)), qy = bf2f((short)(qu >> 16));
    float kx = bf2f((short)(ku & 0xFFFF)), ky = bf2f((short)(ku >> 16));
    float sq = qx * qx + qy * qy;
    float sk = kx * kx + ky * ky;
#pragma unroll
    for (int m = 1; m < 64; m <<= 1) {
      sq += __shfl_xor(sq, m);
      sk += __shfl_xor(sk, m);
    }
    float rq = rsqrtf(sq * (1.f / 128.f) + 1e-5f);
    float rk = rsqrtf(sk * (1.f / 128.f) + 1e-5f);
    float2 wqv = *(const float2*)(wq + 2 * l);
    float2 wkv = *(const float2*)(wk + 2 * l);
    qx = qx * rq * wqv.x; qy = qy * rq * wqv.y;
    kx = kx * rk * wkv.x; ky = ky * rk * wkv.y;
    if (rope) {
      float c = cosb[(size_t)idx * 64 + l];
      float s = sinb[(size_t)idx * 64 + l];
      float t;
      t = qx * c - qy * s; qy = qx * s + qy * c; qx = t;
      t = kx * c - ky * s; ky = kx * s + ky * c; kx = t;
    }
    *(unsigned*)(Qb + off) = pack2(qx, qy);
    *(unsigned*)(Kb + off) = pack2(kx, ky);
  } else {
    // ---- V [h][n][128] -> VT [h][128][n], flattened (36 x 2 x 24) ----
    int j = bid - 13824;
    int bx = j % 36;
    int byz = j / 36;
    int by = byz & 1;
    int h = byz >> 1;
    int n0 = bx * 64, d0 = by * 64;
    int tid = threadIdx.x;
#pragma unroll
    for (int it = 0; it < 2; ++it) {
      int nl = it * 32 + (tid >> 3);
      int dl = (tid & 7) * 8;
      *(bf16x8*)&tile[nl][dl] = *(const bf16x8*)(V + ((size_t)h * NTOT + n0 + nl) * 128 + d0 + dl);
    }
    __syncthreads();
#pragma unroll
    for (int it = 0; it < 2; ++it) {
      int dl = it * 32 + (tid >> 3);
      int nl = (tid & 7) * 8;
      bf16x8 o;
#pragma unroll
      for (int jj = 0; jj < 8; ++jj) o[jj] = tile[nl + jj][dl];
      *(bf16x8*)(VT + ((size_t)h * 128 + d0 + dl) * NTOT + n0 + nl) = o;
    }
  }
}

// ---------------- flash attention: exp2 softmax, cvtpk, extended K swizzle (R10) ----------
__global__ __launch_bounds__(256, 2) void k_attn32(const short* __restrict__ Qb,
                                                   const short* __restrict__ Kb,
                                                   const short* __restrict__ VT,
                                                   const int* __restrict__ seqlens,
                                                   short* __restrict__ Ob) {
  __shared__ __align__(16) char lds[65536];
  const int tid = threadIdx.x;
  const int w = tid >> 6, l = tid & 63;
  const int l31 = l & 31, hi = l >> 5;
  int orig = blockIdx.x;
  int wg = (orig & 7) * 54 + (orig >> 3);
  int h = wg / 18, qb = wg - h * 18;
  const int q0 = qb * 128;
  const size_t hK = (size_t)h * NTOT * 128;
  const size_t hV = (size_t)h * 128 * NTOT;
  const int kvlim = 2048 + seqlens[0];
  const int nt = (kvlim + 63) >> 6;

  // Q prescaled by log2(e)/sqrt(128): softmax runs in exp2 domain
  const float qs = 0.08838834764831845f * 1.44269504088896340f;
  bf16x8 qf[8];
  {
    const short* qrow = Qb + hK + (size_t)(q0 + w * 32 + l31) * 128;
#pragma unroll
    for (int s = 0; s < 8; ++s) {
      bf16x8 r = *(const bf16x8*)(qrow + s * 16 + hi * 8);
      union { unsigned u[4]; bf16x8 b; } cv;
#pragma unroll
      for (int d = 0; d < 4; ++d)
        cv.u[d] = cvtpk(bf2f(r[2 * d]) * qs, bf2f(r[2 * d + 1]) * qs);
      qf[s] = cv.b;
    }
  }

  f32x16 acc[4];
#pragma unroll
  for (int d0 = 0; d0 < 4; ++d0)
#pragma unroll
    for (int r = 0; r < 16; ++r) acc[d0][r] = 0.f;
  float mrun = -1e30f, lsum = 0.f;

  auto stage = [&](int t, int buf) {
    int kv0 = t * 64;
    char* bK = lds + buf * 32768;
    char* bV = bK + 16384;
#pragma unroll
    for (int it = 0; it < 4; ++it) {
      int o = it * 4096 + tid * 16;
      int rk = o >> 8, sk = (o >> 4) & 15;
      int mk = (rk & 7) ^ ((rk >> 3) & 3);
      gload_lds16(Kb + hK + (size_t)(kv0 + rk) * 128 + ((sk ^ mk) << 3), bK + o);
      int rv = o >> 7, sv = (o >> 4) & 7;
      gload_lds16(VT + hV + (size_t)rv * NTOT + kv0 + ((sv ^ (rv & 7)) << 3), bV + o);
    }
  };

  stage(0, 0);
  asm volatile("s_waitcnt vmcnt(0)");
  __syncthreads();

  int cur = 0;
  for (int t = 0; t < nt; ++t) {
    if (t + 1 < nt) stage(t + 1, cur ^ 1);
    const char* bK = lds + cur * 32768;
    const char* bV = bK + 16384;
    f32x16 st[2];
#pragma unroll
    for (int hf = 0; hf < 2; ++hf)
#pragma unroll
      for (int r = 0; r < 16; ++r) st[hf][r] = 0.f;
#pragma unroll
    for (int hf = 0; hf < 2; ++hf) {
      int row = hf * 32 + l31;
      int mk = (row & 7) ^ ((row >> 3) & 3);
#pragma unroll
      for (int s = 0; s < 8; ++s) {
        bf16x8 kf = *(const bf16x8*)(bK + row * 256 + (((s * 2 + hi) ^ mk) << 4));
        st[hf] = __builtin_amdgcn_mfma_f32_32x32x16_bf16(kf, qf[s], st[hf], 0, 0, 0);
      }
    }
    if (t == nt - 1) {
      int kv0 = t * 64;
#pragma unroll
      for (int hf = 0; hf < 2; ++hf)
#pragma unroll
        for (int r = 0; r < 16; ++r) {
          int kv = kv0 + hf * 32 + (r & 3) + 8 * (r >> 2) + 4 * hi;
          if (kv >= kvlim) st[hf][r] = -1e30f;
        }
    }
    float tm[8];
#pragma unroll
    for (int i = 0; i < 8; ++i)
      tm[i] = fmaxf(fmaxf(st[0][2 * i], st[0][2 * i + 1]),
                    fmaxf(st[1][2 * i], st[1][2 * i + 1]));
    float tmax = fmaxf(fmaxf(fmaxf(tm[0], tm[1]), fmaxf(tm[2], tm[3])),
                       fmaxf(fmaxf(tm[4], tm[5]), fmaxf(tm[6], tm[7])));
    tmax = fmaxf(tmax, __shfl_xor(tmax, 32));
    if (!__all(tmax - mrun <= 11.54f)) {
      float mnew = fmaxf(mrun, tmax);
      float corr = __builtin_amdgcn_exp2f(mrun - mnew);
      mrun = mnew;
      lsum *= corr;
#pragma unroll
      for (int d0 = 0; d0 < 4; ++d0)
#pragma unroll
        for (int r = 0; r < 16; ++r) acc[d0][r] *= corr;
    }
    float ts = 0.f;
#pragma unroll
    for (int hf = 0; hf < 2; ++hf)
#pragma unroll
      for (int r = 0; r < 16; ++r) {
        float p = __builtin_amdgcn_exp2f(st[hf][r] - mrun);
        st[hf][r] = p;
        ts += p;
      }
    ts += __shfl_xor(ts, 32);
    lsum += ts;
    bf16x8 pa[4];
#pragma unroll
    for (int hf = 0; hf < 2; ++hf) {
      unsigned x0 = cvtpk(st[hf][0], st[hf][1]);
      unsigned y0 = cvtpk(st[hf][4], st[hf][5]);
      pl32swap(x0, y0);
      unsigned z0 = cvtpk(st[hf][2], st[hf][3]);
      unsigned w0 = cvtpk(st[hf][6], st[hf][7]);
      pl32swap(z0, w0);
      { union { u32x4 u; bf16x8 b; } cv; cv.u = (u32x4){x0, z0, y0, w0}; pa[hf * 2 + 0] = cv.b; }
      unsigned x1 = cvtpk(st[hf][8], st[hf][9]);
      unsigned y1 = cvtpk(st[hf][12], st[hf][13]);
      pl32swap(x1, y1);
      unsigned z1 = cvtpk(st[hf][10], st[hf][11]);
      unsigned w1 = cvtpk(st[hf][14], st[hf][15]);
      pl32swap(z1, w1);
      { union { u32x4 u; bf16x8 b; } cv; cv.u = (u32x4){x1, z1, y1, w1}; pa[hf * 2 + 1] = cv.b; }
    }
#pragma unroll
    for (int d0 = 0; d0 < 4; ++d0) {
      int row = d0 * 32 + l31;
      int rx = row & 7;
#pragma unroll
      for (int s4 = 0; s4 < 4; ++s4) {
        bf16x8 va = *(const bf16x8*)(bV + row * 128 + (((s4 * 2 + hi) ^ rx) << 4));
        acc[d0] = __builtin_amdgcn_mfma_f32_32x32x16_bf16(va, pa[s4], acc[d0], 0, 0, 0);
      }
    }
    asm volatile("s_waitcnt vmcnt(0)");
    __syncthreads();
    cur ^= 1;
  }

  {
    char* ob = lds;
    int qloc = w * 32 + l31;
    int qg = q0 + qloc;
    float inv = (qg < kvlim) ? 1.f / lsum : 0.f;
#pragma unroll
    for (int d0 = 0; d0 < 4; ++d0)
#pragma unroll
      for (int g = 0; g < 4; ++g) {
        int dbase = d0 * 32 + 8 * g + 4 * hi;
        uint2 pk;
        pk.x = cvtpk(acc[d0][4 * g + 0] * inv, acc[d0][4 * g + 1] * inv);
        pk.y = cvtpk(acc[d0][4 * g + 2] * inv, acc[d0][4 * g + 3] * inv);
        int off = dbase * 2;
        int off2 = ((((off >> 4) ^ (qloc & 7)) << 4) | (off & 8));
        *(uint2*)(ob + qloc * 256 + off2) = pk;
      }
    __syncthreads();
    int qr = tid >> 1, dh = tid & 1;
#pragma unroll
    for (int j = 0; j < 8; ++j) {
      int slot = dh * 8 + j;
      bf16x8 v = *(const bf16x8*)(ob + qr * 256 + ((slot ^ (qr & 7)) << 4));
      *(bf16x8*)(Ob + (size_t)(q0 + qr) * 3072 + h * 128 + slot * 8) = v;
    }
  }
}

extern "C" void kernel_launch(void* const* d_in, const int* in_sizes, int n_in,
                              void* d_out, int out_size, void* d_ws, size_t ws_size,
                              hipStream_t stream) {
  const float* x       = (const float*)d_in[0];
  const float* y       = (const float*)d_in[1];
  const float* scale_x = (const float*)d_in[2];
  const float* scale_y = (const float*)d_in[3];
  const float* ropec   = (const float*)d_in[4];
  const float* ropes   = (const float*)d_in[5];
  const int*   seqlens = (const int*)d_in[6];
  const float* Wqx     = (const float*)d_in[7];
  const float* bqx     = (const float*)d_in[8];
  const float* Wqy     = (const float*)d_in[9];
  const float* bqy     = (const float*)d_in[10];
  const float* wqnx    = (const float*)d_in[11];
  const float* wknx    = (const float*)d_in[12];
  const float* wqny    = (const float*)d_in[13];
  const float* wkny    = (const float*)d_in[14];
  const float* Wpx     = (const float*)d_in[15];
  const float* bpx     = (const float*)d_in[16];
  const float* Wpy     = (const float*)d_in[17];
  const float* bpy     = (const float*)d_in[18];
  float* out = (float*)d_out;
  (void)in_sizes; (void)n_in; (void)out_size; (void)ws_size;

  char* ws = (char*)d_ws;
  size_t off = 0;
  auto alloc = [&](size_t bytes) {
    char* p = ws + off;
    off += (bytes + 255) & ~(size_t)255;
    return p;
  };
  short* xm   = (short*)alloc((size_t)2048 * 3072 * 2);
  short* ym   = (short*)alloc((size_t)256 * 1536 * 2);
  short* wqxb = (short*)alloc((size_t)9216 * 3072 * 2);
  short* wqyb = (short*)alloc((size_t)9216 * 1536 * 2);
  short* wpxb = (short*)alloc((size_t)3072 * 3072 * 2);
  short* wpyb = (short*)alloc((size_t)1536 * 3072 * 2);
  short* Qb   = (short*)alloc((size_t)24 * NTOT * 128 * 2);
  short* Kb   = (short*)alloc((size_t)24 * NTOT * 128 * 2);
  short* Vb   = (short*)alloc((size_t)24 * NTOT * 128 * 2);
  short* VTb  = (short*)alloc((size_t)24 * NTOT * 128 * 2);
  short* AO   = (short*)alloc((size_t)NTOT * 3072 * 2);

  hipLaunchKernelGGL(k_modnorm, dim3(2304), dim3(256), 0, stream, x, scale_x, xm, y, scale_y, ym);
  hipLaunchKernelGGL(k_cvt4, dim3(2048), dim3(256), 0, stream,
                     Wqx, wqxb, 9216 * 3072 / 4, Wqy, wqyb, 9216 * 1536 / 4,
                     Wpx, wpxb, 3072 * 3072 / 4, Wpy, wpyb, 1536 * 3072 / 4);
  hipLaunchKernelGGL(k_g256, dim3(32, 8), dim3(512), 0, stream, xm, wqxb, bqx, Qb, Kb, Vb, 3072);
  // merged: qkv_x tail (128 blocks) + qkv_y (144 blocks)
  hipLaunchKernelGGL(k_gemm_qkv2, dim3(272), dim3(256), 0, stream,
                     xm, wqxb + (size_t)8192 * 3072, bqx, ym, wqyb, bqy, Qb, Kb, Vb);
  // merged: qkv post (13824 blocks) + V transpose (1728 blocks)
  hipLaunchKernelGGL(k_post2t, dim3(15552), dim3(256), 0, stream, Qb, Kb,
                     wqnx, wknx, wqny, wkny, ropec, ropes, Vb, VTb);
  hipLaunchKernelGGL(k_attn32, dim3(432), dim3(256), 0, stream, Qb, Kb, VTb, seqlens, AO);
  // merged: proj_x (384 blocks) + proj_y (24 blocks)
  hipLaunchKernelGGL(k_gemm2, dim3(408), dim3(256), 0, stream,
                     AO, wpxb, bpx, out,
                     AO + (size_t)2048 * 3072, wpyb, bpy, out + (size_t)2048 * 3072);
}

// Round 20
// 405.528 us; speedup vs baseline: 1.0131x; 1.0131x over previous
//
#include <hip/hip_runtime.h>
#include <stdint.h>

#define DEV __device__ __forceinline__

typedef __attribute__((ext_vector_type(8))) short bf16x8;
typedef __attribute__((ext_vector_type(4))) float f32x4;
typedef __attribute__((ext_vector_type(16))) float f32x16;
typedef __attribute__((ext_vector_type(4))) unsigned u32x4;

#define NTOT 2304

DEV unsigned short f2bf(float f) {
  union { float f; unsigned u; } c; c.f = f;
  return (unsigned short)((c.u + 0x7FFFu + ((c.u >> 16) & 1u)) >> 16);
}
DEV unsigned pack2(float lo, float hi) {
  return ((unsigned)f2bf(hi) << 16) | (unsigned)f2bf(lo);
}
DEV unsigned cvtpk(float lo, float hi) {
  unsigned r;
  asm("v_cvt_pk_bf16_f32 %0, %1, %2" : "=v"(r) : "v"(lo), "v"(hi));
  return r;
}
DEV float bf2f(short x) {
  union { unsigned u; float f; } c; c.u = ((unsigned)(unsigned short)x) << 16; return c.f;
}
DEV void gload_lds16(const void* g, void* l) {
  __builtin_amdgcn_global_load_lds(
      (const __attribute__((address_space(1))) unsigned int*)g,
      (__attribute__((address_space(3))) unsigned int*)l, 16, 0, 0);
}
DEV void pl32swap(unsigned& a, unsigned& b) {
  asm volatile("v_permlane32_swap_b32 %0, %1" : "+v"(a), "+v"(b));
}

// ---------------- fused prep: modnorm (blocks 0..2303) + 4-segment weight cvt ----------------
__global__ __launch_bounds__(256) void k_prep(const float* __restrict__ X,
                                              const float* __restrict__ scale_x,
                                              short* __restrict__ outx,
                                              const float* __restrict__ Y,
                                              const float* __restrict__ scale_y,
                                              short* __restrict__ outy,
                                              const float* __restrict__ s0, short* __restrict__ d0, int n0,
                                              const float* __restrict__ s1, short* __restrict__ d1, int n1,
                                              const float* __restrict__ s2, short* __restrict__ d2, int n2,
                                              const float* __restrict__ s3, short* __restrict__ d3, int n3) {
  int bid = blockIdx.x;
  if (bid < 2304) {
    // ---- modnorm ----
    int row = bid;
    const float* x;
    const float* scale;
    short* o;
    int D;
    if (row < 2048) {
      x = X + (size_t)row * 3072; scale = scale_x; o = outx + (size_t)row * 3072; D = 3072;
    } else {
      row -= 2048;
      x = Y + (size_t)row * 1536; scale = scale_y; o = outy + (size_t)row * 1536; D = 1536;
    }
    float ss = 0.f;
    for (int v = threadIdx.x * 4; v < D; v += 1024) {
      float4 a = *(const float4*)(x + v);
      ss += a.x * a.x + a.y * a.y + a.z * a.z + a.w * a.w;
    }
#pragma unroll
    for (int m = 1; m < 64; m <<= 1) ss += __shfl_xor(ss, m);
    __shared__ float red[4];
    if ((threadIdx.x & 63) == 0) red[threadIdx.x >> 6] = ss;
    __syncthreads();
    float tot = red[0] + red[1] + red[2] + red[3];
    float r = rsqrtf(tot / (float)D + 1e-6f);
    for (int v = threadIdx.x * 4; v < D; v += 1024) {
      float4 a = *(const float4*)(x + v);
      float4 s = *(const float4*)(scale + v);
      uint2 pk;
      pk.x = pack2(a.x * r * (1.f + s.x), a.y * r * (1.f + s.y));
      pk.y = pack2(a.z * r * (1.f + s.z), a.w * r * (1.f + s.w));
      *(uint2*)(o + v) = pk;
    }
  } else {
    // ---- weight f32 -> bf16 cvt, grid-stride over 4 segments ----
    int total = n0 + n1 + n2 + n3;
    int stride = (gridDim.x - 2304) * 256;
    for (int i = (bid - 2304) * 256 + threadIdx.x; i < total; i += stride) {
      const float* s; short* d; int j = i;
      if (j < n0) { s = s0; d = d0; }
      else {
        j -= n0;
        if (j < n1) { s = s1; d = d1; }
        else {
          j -= n1;
          if (j < n2) { s = s2; d = d2; }
          else { j -= n2; s = s3; d = d3; }
        }
      }
      float4 a = *(const float4*)(s + (size_t)j * 4);
      uint2 pk;
      pk.x = pack2(a.x, a.y);
      pk.y = pack2(a.z, a.w);
      *(uint2*)(d + (size_t)j * 4) = pk;
    }
  }
}

// ---------------- merged proj GEMM: proj_x (blocks 0..383) + proj_y (384..407) ----------
__global__ __launch_bounds__(256) void k_gemm2(const short* __restrict__ A1,
                                               const short* __restrict__ B1,
                                               const float* __restrict__ b1,
                                               float* __restrict__ C1,
                                               const short* __restrict__ A2,
                                               const short* __restrict__ B2,
                                               const float* __restrict__ b2,
                                               float* __restrict__ C2) {
  const int K = 3072;
  int bid = blockIdx.x;
  const short* A; const short* B; const float* bias; float* C;
  int bx, by, N;
  if (bid < 384) {
    bx = bid % 24; by = bid / 24;
    A = A1; B = B1; bias = b1; C = C1; N = 3072;
  } else {
    int j = bid - 384;
    bx = j % 12; by = j / 12;
    A = A2; B = B2; bias = b2; C = C2; N = 1536;
  }
  __shared__ __align__(16) char As[16384];
  __shared__ __align__(16) char Bs[16384];
  const int tid = threadIdx.x;
  const int brow = by * 128, bcol = bx * 128;
  const int w = tid >> 6, l = tid & 63;
  const int wr = (w >> 1) * 64, wc = (w & 1) * 64;
  const int lr = l & 15, lg = l >> 4;
  f32x4 acc[4][4];
#pragma unroll
  for (int m = 0; m < 4; ++m)
#pragma unroll
    for (int n = 0; n < 4; ++n) acc[m][n] = (f32x4){0.f, 0.f, 0.f, 0.f};
  for (int k0 = 0; k0 < K; k0 += 64) {
#pragma unroll
    for (int it = 0; it < 4; ++it) {
      int o = it * 4096 + tid * 16;
      int row = o >> 7;
      int gs = ((o >> 4) & 7) ^ (row & 7);
      gload_lds16(A + (size_t)(brow + row) * K + k0 + gs * 8, As + o);
      gload_lds16(B + (size_t)(bcol + row) * K + k0 + gs * 8, Bs + o);
    }
    __syncthreads();
#pragma unroll
    for (int ks = 0; ks < 2; ++ks) {
      bf16x8 af[4], bfr[4];
#pragma unroll
      for (int m = 0; m < 4; ++m) {
        int ra = wr + m * 16 + lr;
        af[m] = *(const bf16x8*)(As + ra * 128 + (((ks * 4 + lg) ^ (ra & 7)) << 4));
        int rb = wc + m * 16 + lr;
        bfr[m] = *(const bf16x8*)(Bs + rb * 128 + (((ks * 4 + lg) ^ (rb & 7)) << 4));
      }
#pragma unroll
      for (int m = 0; m < 4; ++m)
#pragma unroll
        for (int n = 0; n < 4; ++n)
          acc[m][n] = __builtin_amdgcn_mfma_f32_16x16x32_bf16(bfr[n], af[m], acc[m][n], 0, 0, 0);
    }
    __syncthreads();
  }
#pragma unroll
  for (int m = 0; m < 4; ++m) {
    int row = brow + wr + m * 16 + lr;
#pragma unroll
    for (int n = 0; n < 4; ++n) {
      int col = bcol + wc + n * 16 + lg * 4;
      float4 bv = *(const float4*)(bias + col);
      float4 o;
      o.x = acc[m][n][0] + bv.x;
      o.y = acc[m][n][1] + bv.y;
      o.z = acc[m][n][2] + bv.z;
      o.w = acc[m][n][3] + bv.w;
      *(float4*)(C + (size_t)row * N + col) = o;
    }
  }
}

// ---------------- merged qkv GEMM: x-tail (blocks 0..127) + y (128..271) ----------------
__global__ __launch_bounds__(256) void k_gemm_qkv2(const short* __restrict__ Ax,
                                                   const short* __restrict__ Bx,
                                                   const float* __restrict__ biasx,
                                                   const short* __restrict__ Ay,
                                                   const short* __restrict__ By,
                                                   const float* __restrict__ biasy,
                                                   short* __restrict__ Qb, short* __restrict__ Kb,
                                                   short* __restrict__ Vb) {
  int bid = blockIdx.x;
  const short* A; const short* B; const float* bias;
  int K, col0, base_n, bx, by;
  if (bid < 128) {
    bx = bid & 7; by = bid >> 3;
    A = Ax; B = Bx; bias = biasx; K = 3072; col0 = 8192; base_n = 0;
  } else {
    int j = bid - 128;
    bx = j % 72; by = j / 72;
    A = Ay; B = By; bias = biasy; K = 1536; col0 = 0; base_n = 2048;
  }
  __shared__ __align__(16) char As[16384];
  __shared__ __align__(16) char Bs[16384];
  const int tid = threadIdx.x;
  const int brow = by * 128, bcol = bx * 128;
  const int w = tid >> 6, l = tid & 63;
  const int wr = (w >> 1) * 64, wc = (w & 1) * 64;
  const int lr = l & 15, lg = l >> 4;
  f32x4 acc[4][4];
#pragma unroll
  for (int m = 0; m < 4; ++m)
#pragma unroll
    for (int n = 0; n < 4; ++n) acc[m][n] = (f32x4){0.f, 0.f, 0.f, 0.f};
  for (int k0 = 0; k0 < K; k0 += 64) {
#pragma unroll
    for (int it = 0; it < 4; ++it) {
      int o = it * 4096 + tid * 16;
      int row = o >> 7;
      int gs = ((o >> 4) & 7) ^ (row & 7);
      gload_lds16(A + (size_t)(brow + row) * K + k0 + gs * 8, As + o);
      gload_lds16(B + (size_t)(bcol + row) * K + k0 + gs * 8, Bs + o);
    }
    __syncthreads();
#pragma unroll
    for (int ks = 0; ks < 2; ++ks) {
      bf16x8 af[4], bfr[4];
#pragma unroll
      for (int m = 0; m < 4; ++m) {
        int ra = wr + m * 16 + lr;
        af[m] = *(const bf16x8*)(As + ra * 128 + (((ks * 4 + lg) ^ (ra & 7)) << 4));
        int rb = wc + m * 16 + lr;
        bfr[m] = *(const bf16x8*)(Bs + rb * 128 + (((ks * 4 + lg) ^ (rb & 7)) << 4));
      }
#pragma unroll
      for (int m = 0; m < 4; ++m)
#pragma unroll
        for (int n = 0; n < 4; ++n)
          acc[m][n] = __builtin_amdgcn_mfma_f32_16x16x32_bf16(bfr[n], af[m], acc[m][n], 0, 0, 0);
    }
    __syncthreads();
  }
#pragma unroll
  for (int m = 0; m < 4; ++m) {
    int row = brow + wr + m * 16 + lr;
#pragma unroll
    for (int n = 0; n < 4; ++n) {
      int colg = col0 + bcol + wc + n * 16 + lg * 4;
      float4 bv = *(const float4*)(bias + colg);
      int ty = colg / 3072;
      int rem = colg - ty * 3072;
      int h = rem >> 7, d = rem & 127;
      short* dst = (ty == 0) ? Qb : ((ty == 1) ? Kb : Vb);
      uint2 pk;
      pk.x = pack2(acc[m][n][0] + bv.x, acc[m][n][1] + bv.y);
      pk.y = pack2(acc[m][n][2] + bv.z, acc[m][n][3] + bv.w);
      *(uint2*)(dst + ((size_t)(h * NTOT + base_n + row)) * 128 + d) = pk;
    }
  }
}

// ---------------- 256x256 pipelined GEMM, bf16 qkv epilogue ----------------
__global__ __launch_bounds__(512, 2) void k_g256(const short* __restrict__ A,
                                                 const short* __restrict__ B,
                                                 const float* __restrict__ bias,
                                                 short* __restrict__ Qb, short* __restrict__ Kb,
                                                 short* __restrict__ Vb, int K) {
  __shared__ __align__(16) char lds[131072];  // 2 x (A 32K | B 32K)
  const int tid = threadIdx.x;
  const int w = tid >> 6, l = tid & 63;
  const int lr = l & 15, lg = l >> 4;
  const int wm = w >> 2, wn = w & 3;
  const int brow = blockIdx.y * 256, bcol = blockIdx.x * 256;
  const int nt = K >> 6;

  auto issue = [&](int g) {
    if (g >= 4 * nt) return;
    int tt = g >> 2, hh = g & 3;
    char* base = lds + (tt & 1) * 65536;
    if (hh < 2) {
#pragma unroll
      for (int j = 0; j < 2; ++j) {
        int ch = hh * 1024 + j * 512 + tid;
        int row = ch >> 3, c = ch & 7;
        gload_lds16(A + (size_t)(brow + row) * K + tt * 64 + ((c ^ (row & 7)) << 3),
                    base + ch * 16);
      }
    } else {
      int hb = hh - 2;
#pragma unroll
      for (int j = 0; j < 2; ++j) {
        int ch = hb * 1024 + j * 512 + tid;
        int row = ch >> 3, c = ch & 7;
        gload_lds16(B + (size_t)(bcol + row) * K + tt * 64 + ((c ^ (row & 7)) << 3),
                    base + 32768 + ch * 16);
      }
    }
  };

  f32x4 acc[8][4];
#pragma unroll
  for (int m = 0; m < 8; ++m)
#pragma unroll
    for (int n = 0; n < 4; ++n) acc[m][n] = (f32x4){0.f, 0.f, 0.f, 0.f};

#pragma unroll
  for (int g = 0; g < 6; ++g) issue(g);
  asm volatile("s_waitcnt vmcnt(4)" ::: "memory");
  __builtin_amdgcn_s_barrier();

  bf16x8 af[8][2], bf[4][2];
  for (int t = 0; t < nt; ++t) {
    const char* bb = lds + (t & 1) * 65536;
    const int g0 = 4 * t + 6;
    // p0
#pragma unroll
    for (int m = 0; m < 4; ++m) {
      int r = wm * 128 + m * 16 + lr;
#pragma unroll
      for (int ks = 0; ks < 2; ++ks)
        af[m][ks] = *(const bf16x8*)(bb + r * 128 + (((ks * 4 + lg) ^ (r & 7)) << 4));
    }
#pragma unroll
    for (int n = 0; n < 2; ++n) {
      int r = wn * 64 + n * 16 + lr;
#pragma unroll
      for (int ks = 0; ks < 2; ++ks)
        bf[n][ks] = *(const bf16x8*)(bb + 32768 + r * 128 + (((ks * 4 + lg) ^ (r & 7)) << 4));
    }
    issue(g0);
    __builtin_amdgcn_s_barrier();
    __builtin_amdgcn_s_setprio(1);
#pragma unroll
    for (int m = 0; m < 4; ++m)
#pragma unroll
      for (int n = 0; n < 2; ++n)
#pragma unroll
        for (int ks = 0; ks < 2; ++ks)
          acc[m][n] = __builtin_amdgcn_mfma_f32_16x16x32_bf16(bf[n][ks], af[m][ks], acc[m][n], 0, 0, 0);
    __builtin_amdgcn_s_setprio(0);
    __builtin_amdgcn_sched_barrier(0);
    __builtin_amdgcn_s_barrier();
    // p1
#pragma unroll
    for (int m = 4; m < 8; ++m) {
      int r = wm * 128 + m * 16 + lr;
#pragma unroll
      for (int ks = 0; ks < 2; ++ks)
        af[m][ks] = *(const bf16x8*)(bb + r * 128 + (((ks * 4 + lg) ^ (r & 7)) << 4));
    }
#pragma unroll
    for (int n = 2; n < 4; ++n) {
      int r = wn * 64 + n * 16 + lr;
#pragma unroll
      for (int ks = 0; ks < 2; ++ks)
        bf[n][ks] = *(const bf16x8*)(bb + 32768 + r * 128 + (((ks * 4 + lg) ^ (r & 7)) << 4));
    }
    issue(g0 + 1);
    __builtin_amdgcn_s_barrier();
    __builtin_amdgcn_s_setprio(1);
#pragma unroll
    for (int m = 4; m < 8; ++m)
#pragma unroll
      for (int n = 2; n < 4; ++n)
#pragma unroll
        for (int ks = 0; ks < 2; ++ks)
          acc[m][n] = __builtin_amdgcn_mfma_f32_16x16x32_bf16(bf[n][ks], af[m][ks], acc[m][n], 0, 0, 0);
    __builtin_amdgcn_s_setprio(0);
    __builtin_amdgcn_sched_barrier(0);
    __builtin_amdgcn_s_barrier();
    // p2
    issue(g0 + 2);
    __builtin_amdgcn_s_barrier();
    __builtin_amdgcn_s_setprio(1);
#pragma unroll
    for (int m = 0; m < 4; ++m)
#pragma unroll
      for (int n = 2; n < 4; ++n)
#pragma unroll
        for (int ks = 0; ks < 2; ++ks)
          acc[m][n] = __builtin_amdgcn_mfma_f32_16x16x32_bf16(bf[n][ks], af[m][ks], acc[m][n], 0, 0, 0);
    __builtin_amdgcn_s_setprio(0);
    __builtin_amdgcn_sched_barrier(0);
    __builtin_amdgcn_s_barrier();
    // p3
    issue(g0 + 3);
    __builtin_amdgcn_s_barrier();
    __builtin_amdgcn_s_setprio(1);
#pragma unroll
    for (int m = 4; m < 8; ++m)
#pragma unroll
      for (int n = 0; n < 2; ++n)
#pragma unroll
        for (int ks = 0; ks < 2; ++ks)
          acc[m][n] = __builtin_amdgcn_mfma_f32_16x16x32_bf16(bf[n][ks], af[m][ks], acc[m][n], 0, 0, 0);
    __builtin_amdgcn_s_setprio(0);
    __builtin_amdgcn_sched_barrier(0);
    if (t + 2 < nt)
      asm volatile("s_waitcnt vmcnt(4)" ::: "memory");
    else
      asm volatile("s_waitcnt vmcnt(0)" ::: "memory");
    __builtin_amdgcn_s_barrier();
  }

  // epilogue: bias + packed 8B bf16 stores (lane holds 4 consecutive cols)
#pragma unroll
  for (int m = 0; m < 8; ++m) {
    int row = brow + wm * 128 + m * 16 + lr;
#pragma unroll
    for (int n = 0; n < 4; ++n) {
      int colg = bcol + wn * 64 + n * 16 + lg * 4;
      float4 bv = *(const float4*)(bias + colg);
      int ty = colg / 3072;
      int rem = colg - ty * 3072;
      int h = rem >> 7, d = rem & 127;
      short* dst = (ty == 0) ? Qb : ((ty == 1) ? Kb : Vb);
      uint2 pk;
      pk.x = pack2(acc[m][n][0] + bv.x, acc[m][n][1] + bv.y);
      pk.y = pack2(acc[m][n][2] + bv.z, acc[m][n][3] + bv.w);
      *(uint2*)(dst + ((size_t)(h * NTOT + row)) * 128 + d) = pk;
    }
  }
}

// ---------------- merged: qkv post (blocks 0..13823) + V transpose (13824..15551) ----------
__global__ __launch_bounds__(256) void k_post2t(short* __restrict__ Qb, short* __restrict__ Kb,
                                                const float* __restrict__ wqx,
                                                const float* __restrict__ wkx,
                                                const float* __restrict__ wqy,
                                                const float* __restrict__ wky,
                                                const float* __restrict__ cosb,
                                                const float* __restrict__ sinb,
                                                const short* __restrict__ V,
                                                short* __restrict__ VT) {
  __shared__ __align__(16) short tile[64][72];
  int bid = blockIdx.x;
  if (bid < 13824) {
    int idx = bid * 4 + (threadIdx.x >> 6);
    int l = threadIdx.x & 63;
    const float* wq;
    const float* wk;
    int n, h, base_n;
    bool rope;
    if (idx < 49152) {
      n = idx / 24; h = idx - n * 24; base_n = 0; wq = wqx; wk = wkx; rope = true;
    } else {
      int j = idx - 49152;
      n = j / 24; h = j - n * 24; base_n = 2048; wq = wqy; wk = wky; rope = false;
    }
    size_t off = ((size_t)h * NTOT + base_n + n) * 128 + 2 * l;
    unsigned qu = *(unsigned*)(Qb + off);
    unsigned ku = *(unsigned*)(Kb + off);
    float qx = bf2f((short)(qu & 0xFFFF)), qy = bf2f((short)(qu >> 16));
    float kx = bf2f((short)(ku & 0xFFFF)), ky = bf2f((short)(ku >> 16));
    float sq = qx * qx + qy * qy;
    float sk = kx * kx + ky * ky;
#pragma unroll
    for (int m = 1; m < 64; m <<= 1) {
      sq += __shfl_xor(sq, m);
      sk += __shfl_xor(sk, m);
    }
    float rq = rsqrtf(sq * (1.f / 128.f) + 1e-5f);
    float rk = rsqrtf(sk * (1.f / 128.f) + 1e-5f);
    float2 wqv = *(const float2*)(wq + 2 * l);
    float2 wkv = *(const float2*)(wk + 2 * l);
    qx = qx * rq * wqv.x; qy = qy * rq * wqv.y;
    kx = kx * rk * wkv.x; ky = ky * rk * wkv.y;
    if (rope) {
      float c = cosb[(size_t)idx * 64 + l];
      float s = sinb[(size_t)idx * 64 + l];
      float t;
      t = qx * c - qy * s; qy = qx * s + qy * c; qx = t;
      t = kx * c - ky * s; ky = kx * s + ky * c; kx = t;
    }
    *(unsigned*)(Qb + off) = pack2(qx, qy);
    *(unsigned*)(Kb + off) = pack2(kx, ky);
  } else {
    int j = bid - 13824;
    int bx = j % 36;
    int byz = j / 36;
    int by = byz & 1;
    int h = byz >> 1;
    int n0 = bx * 64, d0 = by * 64;
    int tid = threadIdx.x;
#pragma unroll
    for (int it = 0; it < 2; ++it) {
      int nl = it * 32 + (tid >> 3);
      int dl = (tid & 7) * 8;
      *(bf16x8*)&tile[nl][dl] = *(const bf16x8*)(V + ((size_t)h * NTOT + n0 + nl) * 128 + d0 + dl);
    }
    __syncthreads();
#pragma unroll
    for (int it = 0; it < 2; ++it) {
      int dl = it * 32 + (tid >> 3);
      int nl = (tid & 7) * 8;
      bf16x8 o;
#pragma unroll
      for (int jj = 0; jj < 8; ++jj) o[jj] = tile[nl + jj][dl];
      *(bf16x8*)(VT + ((size_t)h * 128 + d0 + dl) * NTOT + n0 + nl) = o;
    }
  }
}

// ---------------- flash attention: exp2 softmax, cvtpk, extended K swizzle ----------
__global__ __launch_bounds__(256, 2) void k_attn32(const short* __restrict__ Qb,
                                                   const short* __restrict__ Kb,
                                                   const short* __restrict__ VT,
                                                   const int* __restrict__ seqlens,
                                                   short* __restrict__ Ob) {
  __shared__ __align__(16) char lds[65536];
  const int tid = threadIdx.x;
  const int w = tid >> 6, l = tid & 63;
  const int l31 = l & 31, hi = l >> 5;
  int orig = blockIdx.x;
  int wg = (orig & 7) * 54 + (orig >> 3);
  int h = wg / 18, qb = wg - h * 18;
  const int q0 = qb * 128;
  const size_t hK = (size_t)h * NTOT * 128;
  const size_t hV = (size_t)h * 128 * NTOT;
  const int kvlim = 2048 + seqlens[0];
  const int nt = (kvlim + 63) >> 6;

  const float qs = 0.08838834764831845f * 1.44269504088896340f;
  bf16x8 qf[8];
  {
    const short* qrow = Qb + hK + (size_t)(q0 + w * 32 + l31) * 128;
#pragma unroll
    for (int s = 0; s < 8; ++s) {
      bf16x8 r = *(const bf16x8*)(qrow + s * 16 + hi * 8);
      union { unsigned u[4]; bf16x8 b; } cv;
#pragma unroll
      for (int d = 0; d < 4; ++d)
        cv.u[d] = cvtpk(bf2f(r[2 * d]) * qs, bf2f(r[2 * d + 1]) * qs);
      qf[s] = cv.b;
    }
  }

  f32x16 acc[4];
#pragma unroll
  for (int d0 = 0; d0 < 4; ++d0)
#pragma unroll
    for (int r = 0; r < 16; ++r) acc[d0][r] = 0.f;
  float mrun = -1e30f, lsum = 0.f;

  auto stage = [&](int t, int buf) {
    int kv0 = t * 64;
    char* bK = lds + buf * 32768;
    char* bV = bK + 16384;
#pragma unroll
    for (int it = 0; it < 4; ++it) {
      int o = it * 4096 + tid * 16;
      int rk = o >> 8, sk = (o >> 4) & 15;
      int mk = (rk & 7) ^ ((rk >> 3) & 3);
      gload_lds16(Kb + hK + (size_t)(kv0 + rk) * 128 + ((sk ^ mk) << 3), bK + o);
      int rv = o >> 7, sv = (o >> 4) & 7;
      gload_lds16(VT + hV + (size_t)rv * NTOT + kv0 + ((sv ^ (rv & 7)) << 3), bV + o);
    }
  };

  stage(0, 0);
  asm volatile("s_waitcnt vmcnt(0)");
  __syncthreads();

  int cur = 0;
  for (int t = 0; t < nt; ++t) {
    if (t + 1 < nt) stage(t + 1, cur ^ 1);
    const char* bK = lds + cur * 32768;
    const char* bV = bK + 16384;
    f32x16 st[2];
#pragma unroll
    for (int hf = 0; hf < 2; ++hf)
#pragma unroll
      for (int r = 0; r < 16; ++r) st[hf][r] = 0.f;
#pragma unroll
    for (int hf = 0; hf < 2; ++hf) {
      int row = hf * 32 + l31;
      int mk = (row & 7) ^ ((row >> 3) & 3);
#pragma unroll
      for (int s = 0; s < 8; ++s) {
        bf16x8 kf = *(const bf16x8*)(bK + row * 256 + (((s * 2 + hi) ^ mk) << 4));
        st[hf] = __builtin_amdgcn_mfma_f32_32x32x16_bf16(kf, qf[s], st[hf], 0, 0, 0);
      }
    }
    if (t == nt - 1) {
      int kv0 = t * 64;
#pragma unroll
      for (int hf = 0; hf < 2; ++hf)
#pragma unroll
        for (int r = 0; r < 16; ++r) {
          int kv = kv0 + hf * 32 + (r & 3) + 8 * (r >> 2) + 4 * hi;
          if (kv >= kvlim) st[hf][r] = -1e30f;
        }
    }
    float tm[8];
#pragma unroll
    for (int i = 0; i < 8; ++i)
      tm[i] = fmaxf(fmaxf(st[0][2 * i], st[0][2 * i + 1]),
                    fmaxf(st[1][2 * i], st[1][2 * i + 1]));
    float tmax = fmaxf(fmaxf(fmaxf(tm[0], tm[1]), fmaxf(tm[2], tm[3])),
                       fmaxf(fmaxf(tm[4], tm[5]), fmaxf(tm[6], tm[7])));
    tmax = fmaxf(tmax, __shfl_xor(tmax, 32));
    if (!__all(tmax - mrun <= 11.54f)) {
      float mnew = fmaxf(mrun, tmax);
      float corr = __builtin_amdgcn_exp2f(mrun - mnew);
      mrun = mnew;
      lsum *= corr;
#pragma unroll
      for (int d0 = 0; d0 < 4; ++d0)
#pragma unroll
        for (int r = 0; r < 16; ++r) acc[d0][r] *= corr;
    }
    float ts = 0.f;
#pragma unroll
    for (int hf = 0; hf < 2; ++hf)
#pragma unroll
      for (int r = 0; r < 16; ++r) {
        float p = __builtin_amdgcn_exp2f(st[hf][r] - mrun);
        st[hf][r] = p;
        ts += p;
      }
    ts += __shfl_xor(ts, 32);
    lsum += ts;
    bf16x8 pa[4];
#pragma unroll
    for (int hf = 0; hf < 2; ++hf) {
      unsigned x0 = cvtpk(st[hf][0], st[hf][1]);
      unsigned y0 = cvtpk(st[hf][4], st[hf][5]);
      pl32swap(x0, y0);
      unsigned z0 = cvtpk(st[hf][2], st[hf][3]);
      unsigned w0 = cvtpk(st[hf][6], st[hf][7]);
      pl32swap(z0, w0);
      { union { u32x4 u; bf16x8 b; } cv; cv.u = (u32x4){x0, z0, y0, w0}; pa[hf * 2 + 0] = cv.b; }
      unsigned x1 = cvtpk(st[hf][8], st[hf][9]);
      unsigned y1 = cvtpk(st[hf][12], st[hf][13]);
      pl32swap(x1, y1);
      unsigned z1 = cvtpk(st[hf][10], st[hf][11]);
      unsigned w1 = cvtpk(st[hf][14], st[hf][15]);
      pl32swap(z1, w1);
      { union { u32x4 u; bf16x8 b; } cv; cv.u = (u32x4){x1, z1, y1, w1}; pa[hf * 2 + 1] = cv.b; }
    }
#pragma unroll
    for (int d0 = 0; d0 < 4; ++d0) {
      int row = d0 * 32 + l31;
      int rx = row & 7;
#pragma unroll
      for (int s4 = 0; s4 < 4; ++s4) {
        bf16x8 va = *(const bf16x8*)(bV + row * 128 + (((s4 * 2 + hi) ^ rx) << 4));
        acc[d0] = __builtin_amdgcn_mfma_f32_32x32x16_bf16(va, pa[s4], acc[d0], 0, 0, 0);
      }
    }
    asm volatile("s_waitcnt vmcnt(0)");
    __syncthreads();
    cur ^= 1;
  }

  {
    char* ob = lds;
    int qloc = w * 32 + l31;
    int qg = q0 + qloc;
    float inv = (qg < kvlim) ? 1.f / lsum : 0.f;
#pragma unroll
    for (int d0 = 0; d0 < 4; ++d0)
#pragma unroll
      for (int g = 0; g < 4; ++g) {
        int dbase = d0 * 32 + 8 * g + 4 * hi;
        uint2 pk;
        pk.x = cvtpk(acc[d0][4 * g + 0] * inv, acc[d0][4 * g + 1] * inv);
        pk.y = cvtpk(acc[d0][4 * g + 2] * inv, acc[d0][4 * g + 3] * inv);
        int off = dbase * 2;
        int off2 = ((((off >> 4) ^ (qloc & 7)) << 4) | (off & 8));
        *(uint2*)(ob + qloc * 256 + off2) = pk;
      }
    __syncthreads();
    int qr = tid >> 1, dh = tid & 1;
#pragma unroll
    for (int j = 0; j < 8; ++j) {
      int slot = dh * 8 + j;
      bf16x8 v = *(const bf16x8*)(ob + qr * 256 + ((slot ^ (qr & 7)) << 4));
      *(bf16x8*)(Ob + (size_t)(q0 + qr) * 3072 + h * 128 + slot * 8) = v;
    }
  }
}

extern "C" void kernel_launch(void* const* d_in, const int* in_sizes, int n_in,
                              void* d_out, int out_size, void* d_ws, size_t ws_size,
                              hipStream_t stream) {
  const float* x       = (const float*)d_in[0];
  const float* y       = (const float*)d_in[1];
  const float* scale_x = (const float*)d_in[2];
  const float* scale_y = (const float*)d_in[3];
  const float* ropec   = (const float*)d_in[4];
  const float* ropes   = (const float*)d_in[5];
  const int*   seqlens = (const int*)d_in[6];
  const float* Wqx     = (const float*)d_in[7];
  const float* bqx     = (const float*)d_in[8];
  const float* Wqy     = (const float*)d_in[9];
  const float* bqy     = (const float*)d_in[10];
  const float* wqnx    = (const float*)d_in[11];
  const float* wknx    = (const float*)d_in[12];
  const float* wqny    = (const float*)d_in[13];
  const float* wkny    = (const float*)d_in[14];
  const float* Wpx     = (const float*)d_in[15];
  const float* bpx     = (const float*)d_in[16];
  const float* Wpy     = (const float*)d_in[17];
  const float* bpy     = (const float*)d_in[18];
  float* out = (float*)d_out;
  (void)in_sizes; (void)n_in; (void)out_size; (void)ws_size;

  char* ws = (char*)d_ws;
  size_t off = 0;
  auto alloc = [&](size_t bytes) {
    char* p = ws + off;
    off += (bytes + 255) & ~(size_t)255;
    return p;
  };
  short* xm   = (short*)alloc((size_t)2048 * 3072 * 2);
  short* ym   = (short*)alloc((size_t)256 * 1536 * 2);
  short* wqxb = (short*)alloc((size_t)9216 * 3072 * 2);
  short* wqyb = (short*)alloc((size_t)9216 * 1536 * 2);
  short* wpxb = (short*)alloc((size_t)3072 * 3072 * 2);
  short* wpyb = (short*)alloc((size_t)1536 * 3072 * 2);
  short* Qb   = (short*)alloc((size_t)24 * NTOT * 128 * 2);
  short* Kb   = (short*)alloc((size_t)24 * NTOT * 128 * 2);
  short* Vb   = (short*)alloc((size_t)24 * NTOT * 128 * 2);
  short* VTb  = (short*)alloc((size_t)24 * NTOT * 128 * 2);
  short* AO   = (short*)alloc((size_t)NTOT * 3072 * 2);

  // fused: modnorm (2304 blocks) + weight cvt (2048 blocks)
  hipLaunchKernelGGL(k_prep, dim3(4352), dim3(256), 0, stream,
                     x, scale_x, xm, y, scale_y, ym,
                     Wqx, wqxb, 9216 * 3072 / 4, Wqy, wqyb, 9216 * 1536 / 4,
                     Wpx, wpxb, 3072 * 3072 / 4, Wpy, wpyb, 1536 * 3072 / 4);
  hipLaunchKernelGGL(k_g256, dim3(32, 8), dim3(512), 0, stream, xm, wqxb, bqx, Qb, Kb, Vb, 3072);
  // merged: qkv_x tail (128 blocks) + qkv_y (144 blocks)
  hipLaunchKernelGGL(k_gemm_qkv2, dim3(272), dim3(256), 0, stream,
                     xm, wqxb + (size_t)8192 * 3072, bqx, ym, wqyb, bqy, Qb, Kb, Vb);
  // merged: qkv post (13824 blocks) + V transpose (1728 blocks)
  hipLaunchKernelGGL(k_post2t, dim3(15552), dim3(256), 0, stream, Qb, Kb,
                     wqnx, wknx, wqny, wkny, ropec, ropes, Vb, VTb);
  hipLaunchKernelGGL(k_attn32, dim3(432), dim3(256), 0, stream, Qb, Kb, VTb, seqlens, AO);
  // merged: proj_x (384 blocks) + proj_y (24 blocks)
  hipLaunchKernelGGL(k_gemm2, dim3(408), dim3(256), 0, stream,
                     AO, wpxb, bpx, out,
                     AO + (size_t)2048 * 3072, wpyb, bpy, out + (size_t)2048 * 3072);
}